// Round 9
// baseline (863.640 us; speedup 1.0000x reference)
//
#include <hip/hip_runtime.h>
#include <hip/hip_bf16.h>

// GraphSAGE forward. R19: persistent MEGAKERNEL. R18 closed the budget: kernels sum
// to ~89us of 222; the rest is dispatch overhead (26 dispatches/iter incl harness
// restores). Collapse our 10 kernels -> 1 persistent kernel (512 blocks x 256thr,
// launch_bounds(256,2), 48KB LDS -> provably co-resident) with manual grid barriers
// (agent-scope atomics + threadfence for cross-XCD L2 coherence). Phases:
// P0 cvt+packT+hist | P1 psum | P2 scan2 | P3 fill+gemm1(overlap) | P4 gather1
// | P5 gemm2 | P6 gather2 | P7 pool | P8 head.  Dispatches/iter: 11 -> 2.

#define HID 256
#define NCOL 512
#define NB 512
#define NTHR 256

typedef __bf16 bf16x8 __attribute__((ext_vector_type(8)));
typedef float floatx4 __attribute__((ext_vector_type(4)));
typedef ushort ushort8v __attribute__((ext_vector_type(8)));
typedef unsigned int u32;
typedef const u32 __attribute__((address_space(1)))* gp_t;
typedef u32 __attribute__((address_space(3)))* lp_t;

__device__ __forceinline__ ushort f2bf(float f) {   // round-to-nearest-even
    unsigned u = __float_as_uint(f);
    u += 0x7fffu + ((u >> 16) & 1u);
    return (ushort)(u >> 16);
}
__device__ __forceinline__ float bf2f(ushort b) {
    return __uint_as_float(((unsigned)b) << 16);
}

// ---- grid barrier: agent-scope arrive + acquire spin; threadfence gives the
// cross-XCD release/acquire (buffer_wb/inv on gfx950). Requires all NB blocks
// co-resident (guaranteed: 48KB LDS + launch_bounds(256,2) -> >=2 blocks/CU x 256CU).
__device__ __forceinline__ void gsync(u32* bar, int slot) {
    __syncthreads();
    if (threadIdx.x == 0) {
        __threadfence();
        __hip_atomic_fetch_add(bar + slot, 1u, __ATOMIC_RELEASE, __HIP_MEMORY_SCOPE_AGENT);
        while (__hip_atomic_load(bar + slot, __ATOMIC_ACQUIRE, __HIP_MEMORY_SCOPE_AGENT) < NB)
            __builtin_amdgcn_s_sleep(8);
        __threadfence();
    }
    __syncthreads();
}

__device__ __forceinline__ void packT_work(const float* __restrict__ Wn,
                                           const float* __restrict__ Ws,
                                           ushort* __restrict__ WT, int K, int gid) {
    int n = gid / K, k = gid - n * K;
    float v = (n < HID) ? Wn[k * HID + n] : Ws[k * HID + (n - HID)];
    WT[gid] = f2bf(v);
}

// ---- gemm tiles, grid-stride: [Yn|Ys][Mpad,256] = A[Mpad,K] @ BT[512,K]^T
__device__ __forceinline__ void gemm_tiles(const ushort* __restrict__ A,
                                           const ushort* __restrict__ BT,
                                           ushort* __restrict__ Yn, ushort* __restrict__ Ys,
                                           int K, int nG, ushort* As0, ushort* Bs0) {
    int tid = threadIdx.x;
    int w = tid >> 6, lane = tid & 63;
    int quad = lane >> 4, r16 = lane & 15;
    int wm = (w >> 1) * 32, wn = (w & 1) * 64;

    int arow[2], agu[2], brow[4], bgu[4];
#pragma unroll
    for (int rr = 0; rr < 2; ++rr) {
        int idx = rr * 256 + tid;
        arow[rr] = idx >> 3;
        agu[rr] = (idx & 7) ^ (arow[rr] & 7);
    }
#pragma unroll
    for (int rr = 0; rr < 4; ++rr) {
        int idx = rr * 256 + tid;
        brow[rr] = idx >> 3;
        bgu[rr] = (idx & 7) ^ (brow[rr] & 7);
    }

    const int ntile = nG * 4;
    for (int tl = blockIdx.x; tl < ntile; tl += NB) {
        int G = tl >> 2, m = tl & 3;
        int m0 = G * 64, n0 = m * 128;

        auto stage = [&](int buf, int k0) {
#pragma unroll
            for (int rr = 0; rr < 2; ++rr) {
                const ushort* ga = A + (size_t)(m0 + arow[rr]) * K + k0 + agu[rr] * 8;
                ushort* la = As0 + (size_t)buf * 4096 + (size_t)(rr * 256 + w * 64) * 8;
                __builtin_amdgcn_global_load_lds((gp_t)(const void*)ga, (lp_t)(void*)la, 16, 0, 0);
            }
#pragma unroll
            for (int rr = 0; rr < 4; ++rr) {
                const ushort* gb = BT + (size_t)(n0 + brow[rr]) * K + k0 + bgu[rr] * 8;
                ushort* lb = Bs0 + (size_t)buf * 8192 + (size_t)(rr * 256 + w * 64) * 8;
                __builtin_amdgcn_global_load_lds((gp_t)(const void*)gb, (lp_t)(void*)lb, 16, 0, 0);
            }
        };

        floatx4 acc[2][4];
#pragma unroll
        for (int i = 0; i < 2; ++i)
#pragma unroll
            for (int j = 0; j < 4; ++j) acc[i][j] = (floatx4){0.f, 0.f, 0.f, 0.f};

        __syncthreads();                       // WAR vs previous tile's LDS reads
        stage(0, 0);
        const int nk = K >> 6;
        for (int t = 0; t < nk; ++t) {
            int cb = t & 1;
            __syncthreads();
            if (t + 1 < nk) stage(cb ^ 1, (t + 1) << 6);
            const ushort* Ab = As0 + cb * 4096;
            const ushort* Bb = Bs0 + cb * 8192;
#pragma unroll
            for (int s = 0; s < 2; ++s) {
                bf16x8 a[2], b2[4];
#pragma unroll
                for (int i = 0; i < 2; ++i) {
                    int row = wm + i * 16 + r16;
                    int au = (s * 4 + quad) ^ (row & 7);
                    a[i] = *(const bf16x8*)(Ab + row * 64 + au * 8);
                }
#pragma unroll
                for (int j = 0; j < 4; ++j) {
                    int row = wn + j * 16 + r16;
                    int bu = (s * 4 + quad) ^ (row & 7);
                    b2[j] = *(const bf16x8*)(Bb + row * 64 + bu * 8);
                }
#pragma unroll
                for (int i = 0; i < 2; ++i)
#pragma unroll
                    for (int j = 0; j < 4; ++j)
                        acc[i][j] = __builtin_amdgcn_mfma_f32_16x16x32_bf16(a[i], b2[j], acc[i][j], 0, 0, 0);
            }
        }
        ushort* O = (m < 2) ? Yn : Ys;
        int cb0 = (m < 2) ? n0 : (n0 - 256);
#pragma unroll
        for (int i = 0; i < 2; ++i)
#pragma unroll
            for (int j = 0; j < 4; ++j) {
                int col = cb0 + wn + j * 16 + r16;
#pragma unroll
                for (int rg = 0; rg < 4; ++rg) {
                    int row = m0 + wm + i * 16 + quad * 4 + rg;
                    O[(size_t)row * HID + col] = f2bf(acc[i][j][rg]);
                }
            }
    }
}

// ---- gather, wave-per-node grid-stride (half-wave rows, 16 rows in flight/wave)
__device__ __forceinline__ void acc8(float* A, ushort8v y) {
#pragma unroll
    for (int i = 0; i < 8; ++i) A[i] += bf2f((ushort)y[i]);
}

__device__ __forceinline__ void gather_nodes(const ushort* __restrict__ Yn,
                                             const ushort* __restrict__ Ys,
                                             const int* __restrict__ off,
                                             const int* __restrict__ eidx,
                                             const float* __restrict__ bias,
                                             ushort* __restrict__ h, int n_nodes) {
    int tid = threadIdx.x;
    int lane = tid & 63;
    int half = lane >> 5, sub = lane & 31;
    int c8 = sub << 3;
    int w0 = (blockIdx.x << 2) + (tid >> 6);
    for (int v = w0; v < n_nodes; v += NB * 4) {
        int e0 = off[v], e1 = off[v + 1];
        float accA[8] = {0.f, 0.f, 0.f, 0.f, 0.f, 0.f, 0.f, 0.f};
        float accB[8] = {0.f, 0.f, 0.f, 0.f, 0.f, 0.f, 0.f, 0.f};
        for (int base = e0; base < e1; base += 64) {
            int ecnt = min(64, e1 - base);
            int ev = (lane < ecnt) ? eidx[base + lane] : 0;
            int j = 0;
            for (; j + 16 <= ecnt; j += 16) {
                int s0 = __shfl(ev, j + 0 + half, 64);
                int s1 = __shfl(ev, j + 2 + half, 64);
                int s2 = __shfl(ev, j + 4 + half, 64);
                int s3 = __shfl(ev, j + 6 + half, 64);
                int s4 = __shfl(ev, j + 8 + half, 64);
                int s5 = __shfl(ev, j + 10 + half, 64);
                int s6 = __shfl(ev, j + 12 + half, 64);
                int s7 = __shfl(ev, j + 14 + half, 64);
                ushort8v y0 = *(const ushort8v*)(Yn + (size_t)s0 * HID + c8);
                ushort8v y1 = *(const ushort8v*)(Yn + (size_t)s1 * HID + c8);
                ushort8v y2 = *(const ushort8v*)(Yn + (size_t)s2 * HID + c8);
                ushort8v y3 = *(const ushort8v*)(Yn + (size_t)s3 * HID + c8);
                ushort8v y4 = *(const ushort8v*)(Yn + (size_t)s4 * HID + c8);
                ushort8v y5 = *(const ushort8v*)(Yn + (size_t)s5 * HID + c8);
                ushort8v y6 = *(const ushort8v*)(Yn + (size_t)s6 * HID + c8);
                ushort8v y7 = *(const ushort8v*)(Yn + (size_t)s7 * HID + c8);
                acc8(accA, y0); acc8(accB, y1); acc8(accA, y2); acc8(accB, y3);
                acc8(accA, y4); acc8(accB, y5); acc8(accA, y6); acc8(accB, y7);
            }
            for (; j < ecnt; j += 2) {
                int idx = j + half;
                if (idx < ecnt) {
                    int s = __shfl(ev, idx, 64);
                    ushort8v y = *(const ushort8v*)(Yn + (size_t)s * HID + c8);
                    acc8(accA, y);
                }
            }
        }
#pragma unroll
        for (int i = 0; i < 8; ++i) {
            accA[i] += accB[i];
            accA[i] += __shfl_xor(accA[i], 32, 64);
        }
        if (half == 0) {
            ushort8v sv = *(const ushort8v*)(Ys + (size_t)v * HID + c8);
            float bb[8];
            *(float4*)(bb)     = *(const float4*)(bias + c8);
            *(float4*)(bb + 4) = *(const float4*)(bias + c8 + 4);
            float invd = 1.0f / fmaxf((float)(e1 - e0), 1.0f);
            ushort8v r;
#pragma unroll
            for (int i = 0; i < 8; ++i)
                r[i] = f2bf(fmaxf(accA[i] * invd + bf2f((ushort)sv[i]) + bb[i], 0.f));
            *(ushort8v*)(h + (size_t)v * HID + c8) = r;
        }
    }
}

// ================= MEGAKERNEL =================
__global__ __launch_bounds__(NTHR, 2) void mega(
    const float* __restrict__ x, const int* __restrict__ src, const int* __restrict__ dst,
    const int* __restrict__ batch,
    const float* __restrict__ W1n, const float* __restrict__ W1s, const float* __restrict__ b1,
    const float* __restrict__ W2n, const float* __restrict__ W2s, const float* __restrict__ b2,
    const float* __restrict__ fc1w, const float* __restrict__ fc1b,
    const float* __restrict__ fc2w, const float* __restrict__ fc2b,
    float* __restrict__ out,
    int* __restrict__ degi, float* __restrict__ pooled, float* __restrict__ cnt,
    int* __restrict__ off, int* __restrict__ cursor, int* __restrict__ partials,
    int* __restrict__ eidx, ushort* __restrict__ w1t, ushort* __restrict__ w2t,
    ushort* __restrict__ xb, ushort* __restrict__ hb,
    ushort* __restrict__ Yn, ushort* __restrict__ Ys,
    u32* __restrict__ bar,
    int n_nodes, int n_edges, int in_dim, int nG, int nbc, int n4) {

    __shared__ ushort As[2 * 64 * 64];         // 16 KB (also reused as head's p/hid)
    __shared__ ushort Bs[2 * 128 * 64];        // 32 KB
    __shared__ int wsum[4];

    const int tid = threadIdx.x, bid = blockIdx.x;
    const int gthr = bid * NTHR + tid;
    const int GT = NB * NTHR;

    // ---- P0: cvt x->bf16 | packT W1 | packT W2 | degree histogram (degi pre-zeroed)
    for (int i = gthr; i < n4; i += GT) {
        float4 v = ((const float4*)x)[i];
        ushort4 o;
        o.x = f2bf(v.x); o.y = f2bf(v.y); o.z = f2bf(v.z); o.w = f2bf(v.w);
        ((ushort4*)xb)[i] = o;
    }
    for (int g = gthr; g < NCOL * in_dim; g += GT) packT_work(W1n, W1s, w1t, in_dim, g);
    for (int g = gthr; g < NCOL * HID; g += GT) packT_work(W2n, W2s, w2t, HID, g);
    for (int e = gthr; e < n_edges; e += GT) atomicAdd(&degi[dst[e]], 1);
    gsync(bar, 0);

    // ---- P1: psum (per-256-chunk sums)
    for (int c = bid; c < nbc; c += NB) {
        int i = c * 256 + tid;
        int v = (i < n_nodes) ? degi[i] : 0;
#pragma unroll
        for (int d = 1; d < 64; d <<= 1) v += __shfl_xor(v, d, 64);
        if ((tid & 63) == 0) wsum[tid >> 6] = v;
        __syncthreads();
        if (tid == 0) partials[c] = wsum[0] + wsum[1] + wsum[2] + wsum[3];
        __syncthreads();
    }
    gsync(bar, 1);

    // ---- P2: scan2 (chunk prefix + rescan -> off, cursor)
    {
        int lane = tid & 63, w = tid >> 6;
        for (int c = bid; c < nbc; c += NB) {
            int pre = 0, tot = 0;
            for (int base = 0; base < nbc; base += 64) {
                int idx = base + lane;
                int pv = (idx < nbc) ? partials[idx] : 0;
                pre += (idx < c) ? pv : 0;
                tot += pv;
            }
#pragma unroll
            for (int d = 1; d < 64; d <<= 1) {
                pre += __shfl_xor(pre, d, 64);
                tot += __shfl_xor(tot, d, 64);
            }
            if (c == 0 && tid == 0) off[n_nodes] = tot;
            int i = c * 256 + tid;
            int v = (i < n_nodes) ? degi[i] : 0;
            int s = v;
#pragma unroll
            for (int d = 1; d < 64; d <<= 1) {
                int u = __shfl_up(s, d, 64);
                if (lane >= d) s += u;
            }
            if (lane == 63) wsum[w] = s;
            __syncthreads();
            int woff = 0;
            for (int k = 0; k < w; ++k) woff += wsum[k];
            int excl = pre + woff + s - v;
            if (i < n_nodes) { off[i] = excl; cursor[i] = excl; }
            __syncthreads();
        }
    }
    gsync(bar, 2);

    // ---- P3: CSR fill (overlapped with gemm1 — disjoint buffers)
    for (int e = gthr; e < n_edges; e += GT) {
        int p = atomicAdd(&cursor[dst[e]], 1);
        eidx[p] = src[e];
    }
    gemm_tiles(xb, w1t, Yn, Ys, in_dim, nG, As, Bs);
    gsync(bar, 3);

    // ---- P4: gather1
    gather_nodes(Yn, Ys, off, eidx, b1, hb, n_nodes);
    gsync(bar, 4);

    // ---- P5: gemm2
    gemm_tiles(hb, w2t, Yn, Ys, HID, nG, As, Bs);
    gsync(bar, 5);

    // ---- P6: gather2
    gather_nodes(Yn, Ys, off, eidx, b2, hb, n_nodes);
    gsync(bar, 6);

    // ---- P7: pool (segmented, 64-node chunks, atomics into pooled/cnt)
    for (int c = bid; c < (n_nodes + 63) / 64; c += NB) {
        int v0 = c * 64;
        int vend = min(v0 + 64, n_nodes);
        int curg = batch[v0];
        float acc = 0.f, ac = 0.f;
        int f = tid;
        for (int v = v0; v < vend; ++v) {
            int g = batch[v];
            if (g != curg) {
                atomicAdd(&pooled[curg * HID + f], acc);
                if (f == 0) atomicAdd(&cnt[curg], ac);
                acc = 0.f; ac = 0.f; curg = g;
            }
            acc += bf2f(hb[(size_t)v * HID + f]);
            ac += 1.0f;
        }
        atomicAdd(&pooled[curg * HID + f], acc);
        if (f == 0) atomicAdd(&cnt[curg], ac);
    }
    gsync(bar, 7);

    // ---- P8: head (16 blocks; p/hid overlaid on As)
    if (bid < 16) {
        float* hp = (float*)As;                // 256 floats
        float* hh = hp + 256;                  // 128 floats
        int g = bid, j = tid;
        float inv = 1.0f / fmaxf(cnt[g], 1.0f);
        if (j < 128) {
            hp[j] = pooled[g * HID + j] * inv;
            hp[j + 128] = pooled[g * HID + 128 + j] * inv;
        }
        __syncthreads();
        if (j < 128) {
            float a = fc1b[j];
            for (int f = 0; f < 256; ++f) a += hp[f] * fc1w[f * 128 + j];
            hh[j] = fmaxf(a, 0.f);
        }
        __syncthreads();
        if (j < 2) {
            float o = fc2b[j];
            for (int t = 0; t < 128; ++t) o += hh[t] * fc2w[t * 2 + j];
            out[g * 2 + j] = o;
        }
    }
}

extern "C" void kernel_launch(void* const* d_in, const int* in_sizes, int n_in,
                              void* d_out, int out_size, void* d_ws, size_t ws_size,
                              hipStream_t stream) {
    const float* x    = (const float*)d_in[0];
    const int*   ei   = (const int*)d_in[1];
    const int*   batch= (const int*)d_in[2];
    const float* W1n  = (const float*)d_in[3];
    const float* W1s  = (const float*)d_in[4];
    const float* b1   = (const float*)d_in[5];
    const float* W2n  = (const float*)d_in[6];
    const float* W2s  = (const float*)d_in[7];
    const float* b2   = (const float*)d_in[8];
    const float* fc1w = (const float*)d_in[9];
    const float* fc1b = (const float*)d_in[10];
    const float* fc2w = (const float*)d_in[11];
    const float* fc2b = (const float*)d_in[12];
    float* out = (float*)d_out;

    const int n_nodes = in_sizes[2];
    const int n_edges = in_sizes[1] / 2;
    const int in_dim  = in_sizes[0] / n_nodes;   // 512
    const int Mpad    = (n_nodes + 63) & ~63;    // 20032
    const int nbc     = (n_nodes + 255) / 256;   // scan chunks (79)
    const int nG      = Mpad / 64;               // A-stripes (313)
    const int n4      = n_nodes * in_dim / 4;
    const int* src = ei;
    const int* dst = ei + n_edges;

    // workspace layout, 256B-aligned. bar+degi+pooled adjacent -> one small memset.
    char* wsb = (char*)d_ws;
    size_t cur = 0;
    auto alloc = [&](size_t nbytes) { size_t o = cur; cur = (cur + nbytes + 255) & ~(size_t)255; return o; };
    size_t o_bar  = alloc(64);                   // 16 barrier slots
    size_t o_degi = alloc((size_t)n_nodes * 4);
    size_t o_pool = alloc((size_t)16 * HID * 4 + 16 * 4);
    size_t zero_end = cur;                       // memset span [o_bar, zero_end)
    size_t o_off  = alloc((size_t)(n_nodes + 1) * 4);
    size_t o_cur  = alloc((size_t)n_nodes * 4);
    size_t o_part = alloc((size_t)nbc * 4);
    size_t o_eidx = alloc((size_t)n_edges * 4);
    size_t o_w1   = alloc((size_t)NCOL * in_dim * 2);
    size_t o_w2   = alloc((size_t)NCOL * HID * 2);
    size_t o_xb   = alloc((size_t)Mpad * in_dim * 2);
    size_t o_hb   = alloc((size_t)Mpad * HID * 2);
    size_t o_yn   = alloc((size_t)Mpad * HID * 2);
    size_t o_ys   = alloc((size_t)Mpad * HID * 2);
    (void)ws_size;

    u32*    bar     = (u32*)(wsb + o_bar);
    int*    degi    = (int*)(wsb + o_degi);
    float*  pooled  = (float*)(wsb + o_pool);
    float*  cnt     = pooled + 16 * HID;
    int*    off     = (int*)(wsb + o_off);
    int*    cursor  = (int*)(wsb + o_cur);
    int*    partials= (int*)(wsb + o_part);
    int*    eidx    = (int*)(wsb + o_eidx);
    ushort* w1t     = (ushort*)(wsb + o_w1);
    ushort* w2t     = (ushort*)(wsb + o_w2);
    ushort* xb      = (ushort*)(wsb + o_xb);
    ushort* hb      = (ushort*)(wsb + o_hb);
    ushort* Yn      = (ushort*)(wsb + o_yn);
    ushort* Ys      = (ushort*)(wsb + o_ys);

    hipMemsetAsync(wsb + o_bar, 0, zero_end - o_bar, stream);

    mega<<<NB, NTHR, 0, stream>>>(
        x, src, dst, batch, W1n, W1s, b1, W2n, W2s, b2,
        fc1w, fc1b, fc2w, fc2b, out,
        degi, pooled, cnt, off, cursor, partials, eidx,
        w1t, w2t, xb, hb, Yn, Ys, bar,
        n_nodes, n_edges, in_dim, nG, nbc, n4);
}

// Round 10
// 217.138 us; speedup vs baseline: 3.9774x; 3.9774x over previous
//
#include <hip/hip_runtime.h>
#include <hip/hip_bf16.h>

// GraphSAGE forward. R20: revert R19 megakernel (863us: grid-barrier threadfence =
// per-block L2 wb+inv on non-coherent XCDs -> 258MB HBM @ 315GB/s. Megakernels with
// cross-XCD deps are structurally bad on CDNA4). Back to R14/R16 10-dispatch form.
// NEW: (a) xb eliminated — gemm1 is F32A: stages x as f32 + in-staging RNE cvt to
// the same XOR-swizzled LDS slots (drops prep's 60MB cvt pass; identical bf16 bits).
// (b) fill_kernel fused into gemm1's grid (disjoint work, one less boundary).

#define HID 256
#define NCOL 512

typedef __bf16 bf16x8 __attribute__((ext_vector_type(8)));
typedef float floatx4 __attribute__((ext_vector_type(4)));
typedef ushort ushort8v __attribute__((ext_vector_type(8)));
typedef unsigned int u32;
typedef const u32 __attribute__((address_space(1)))* gp_t;
typedef u32 __attribute__((address_space(3)))* lp_t;

__device__ __forceinline__ ushort f2bf(float f) {   // round-to-nearest-even
    unsigned u = __float_as_uint(f);
    u += 0x7fffu + ((u >> 16) & 1u);
    return (ushort)(u >> 16);
}
__device__ __forceinline__ float bf2f(ushort b) {
    return __uint_as_float(((unsigned)b) << 16);
}

// ---------------- prep (lite): [packT W1 | packT W2 | degree histogram]
__device__ __forceinline__ void packT_work(const float* __restrict__ Wn,
                                           const float* __restrict__ Ws,
                                           ushort* __restrict__ WT, int K, int gid) {
    if (gid >= NCOL * K) return;
    int n = gid / K, k = gid - n * K;
    float v = (n < HID) ? Wn[k * HID + n] : Ws[k * HID + (n - HID)];
    WT[gid] = f2bf(v);
}

__global__ void prep_kernel(const float* __restrict__ W1n, const float* __restrict__ W1s,
                            ushort* __restrict__ w1t, int K1,
                            const float* __restrict__ W2n, const float* __restrict__ W2s,
                            ushort* __restrict__ w2t, int K2,
                            const int* __restrict__ dst, int* __restrict__ degi, int n_edges,
                            int nb_w1, int nb_w2) {
    int bx = blockIdx.x, t = threadIdx.x;
    if (bx < nb_w1) {
        packT_work(W1n, W1s, w1t, K1, bx * 256 + t);
    } else if (bx < nb_w1 + nb_w2) {
        packT_work(W2n, W2s, w2t, K2, (bx - nb_w1) * 256 + t);
    } else {
        int e = (bx - nb_w1 - nb_w2) * 256 + t;
        if (e < n_edges) atomicAdd(&degi[dst[e]], 1);
    }
}

// ---------------- scan phase 1: per-256-chunk sums
__global__ __launch_bounds__(256) void psum_kernel(const int* __restrict__ degi,
                                                   int* __restrict__ partials, int n) {
    int t = threadIdx.x;
    int i = blockIdx.x * 256 + t;
    int v = (i < n) ? degi[i] : 0;
#pragma unroll
    for (int d = 1; d < 64; d <<= 1) v += __shfl_xor(v, d, 64);
    __shared__ int wsum[4];
    if ((t & 63) == 0) wsum[t >> 6] = v;
    __syncthreads();
    if (t == 0) partials[blockIdx.x] = wsum[0] + wsum[1] + wsum[2] + wsum[3];
}

// ---------------- scan phase 2 (fused): chunk prefix from partials + rescan.
__global__ __launch_bounds__(256) void scan2_kernel(const int* __restrict__ degi,
                                                    const int* __restrict__ partials,
                                                    int* __restrict__ off,
                                                    int* __restrict__ cursor, int n, int nb) {
    int t = threadIdx.x, lane = t & 63, w = t >> 6;
    int c = blockIdx.x;
    int pre = 0, tot = 0;
    for (int base = 0; base < nb; base += 64) {
        int idx = base + lane;
        int pv = (idx < nb) ? partials[idx] : 0;
        pre += (idx < c) ? pv : 0;
        tot += pv;
    }
#pragma unroll
    for (int d = 1; d < 64; d <<= 1) {
        pre += __shfl_xor(pre, d, 64);
        tot += __shfl_xor(tot, d, 64);
    }
    if (c == 0 && t == 0) off[n] = tot;
    int i = c * 256 + t;
    int v = (i < n) ? degi[i] : 0;
    int s = v;
#pragma unroll
    for (int d = 1; d < 64; d <<= 1) {
        int u = __shfl_up(s, d, 64);
        if (lane >= d) s += u;
    }
    __shared__ int wsum[4];
    if (lane == 63) wsum[w] = s;
    __syncthreads();
    int woff = 0;
    for (int k = 0; k < w; ++k) woff += wsum[k];
    int excl = pre + woff + s - v;
    if (i < n) { off[i] = excl; cursor[i] = excl; }
}

// ---------------- bf16 MFMA GEMM: [Yn|Ys][Mpad,256] = A[Mpad,K] @ BT[512,K]^T
// 64x128 tile, 4 waves, BK=64, dbuf, XOR swizzle, XCD-grouped 1D grid.
// F32A=1: A is f32 (x); stage = per-lane float4 x2 load + RNE cvt + ds_write_b128
//         into the same swizzled slot (identical bits to the old prep cvt).
//         Rows clamped to nClamp-1 (x has exactly n_nodes rows; pad rows unused).
// DOFILL=1: blocks [gemmBlocks, gemmBlocks+fillBlocks) run the CSR fill instead.
template<int F32A, int DOFILL>
__global__ __launch_bounds__(256) void gemm_kernel(const void* __restrict__ Av,
                                                   const ushort* __restrict__ BT,
                                                   ushort* __restrict__ Yn,
                                                   ushort* __restrict__ Ys,
                                                   int K, int nG, int nClamp, int gemmBlocks,
                                                   const int* __restrict__ src,
                                                   const int* __restrict__ dst,
                                                   int* __restrict__ cursor,
                                                   int* __restrict__ eidx, int n_edges) {
    int b = blockIdx.x;
    int tid = threadIdx.x;
    if (DOFILL && b >= gemmBlocks) {           // CSR fill role (disjoint buffers)
        int e = (b - gemmBlocks) * 256 + tid;
        if (e < n_edges) {
            int p = atomicAdd(&cursor[dst[e]], 1);
            eidx[p] = src[e];
        }
        return;
    }
    int xcd = b & 7, rest = b >> 3;
    int m = rest & 3, Ggrp = rest >> 2;
    int G = xcd + 8 * Ggrp;                    // A-stripe id (64 rows)
    if (G >= nG) return;
    int m0 = G * 64, n0 = m * 128;

    __shared__ ushort As[2][64 * 64];
    __shared__ ushort Bs[2][128 * 64];
    int w = tid >> 6, lane = tid & 63;
    int quad = lane >> 4, r16 = lane & 15;
    int wm = (w >> 1) * 32, wn = (w & 1) * 64;

    const ushort* A16 = (const ushort*)Av;
    const float*  A32 = (const float*)Av;

    int arow[2], agu[2], aridx[2], brow[4], bgu[4];
#pragma unroll
    for (int rr = 0; rr < 2; ++rr) {
        int idx = rr * 256 + tid;
        arow[rr] = idx >> 3;
        agu[rr] = (idx & 7) ^ (arow[rr] & 7);
        aridx[rr] = m0 + arow[rr];
        if (F32A) aridx[rr] = min(aridx[rr], nClamp - 1);
    }
#pragma unroll
    for (int rr = 0; rr < 4; ++rr) {
        int idx = rr * 256 + tid;
        brow[rr] = idx >> 3;
        bgu[rr] = (idx & 7) ^ (brow[rr] & 7);
    }

    auto stage = [&](int buf, int k0) {
        if (F32A) {
#pragma unroll
            for (int rr = 0; rr < 2; ++rr) {
                const float* ga = A32 + (size_t)aridx[rr] * K + k0 + agu[rr] * 8;
                float4 u0 = *(const float4*)ga;
                float4 u1 = *(const float4*)(ga + 4);
                ushort8v o;
                o[0] = f2bf(u0.x); o[1] = f2bf(u0.y); o[2] = f2bf(u0.z); o[3] = f2bf(u0.w);
                o[4] = f2bf(u1.x); o[5] = f2bf(u1.y); o[6] = f2bf(u1.z); o[7] = f2bf(u1.w);
                *(ushort8v*)(As[buf] + (size_t)(rr * 256 + tid) * 8) = o;
            }
        } else {
#pragma unroll
            for (int rr = 0; rr < 2; ++rr) {
                const ushort* ga = A16 + (size_t)aridx[rr] * K + k0 + agu[rr] * 8;
                ushort* la = As[buf] + (size_t)(rr * 256 + w * 64) * 8;
                __builtin_amdgcn_global_load_lds((gp_t)(const void*)ga, (lp_t)(void*)la, 16, 0, 0);
            }
        }
#pragma unroll
        for (int rr = 0; rr < 4; ++rr) {
            const ushort* gb = BT + (size_t)(n0 + brow[rr]) * K + k0 + bgu[rr] * 8;
            ushort* lb = Bs[buf] + (size_t)(rr * 256 + w * 64) * 8;
            __builtin_amdgcn_global_load_lds((gp_t)(const void*)gb, (lp_t)(void*)lb, 16, 0, 0);
        }
    };

    floatx4 acc[2][4];
#pragma unroll
    for (int i = 0; i < 2; ++i)
#pragma unroll
        for (int j = 0; j < 4; ++j) acc[i][j] = (floatx4){0.f, 0.f, 0.f, 0.f};

    const int nk = K >> 6;
    stage(0, 0);
    for (int t = 0; t < nk; ++t) {
        int cb = t & 1;
        __syncthreads();                       // drains glds (vmcnt) + ds_writes (lgkm)
        if (t + 1 < nk) stage(cb ^ 1, (t + 1) << 6);
        const ushort* Ab = As[cb];
        const ushort* Bb = Bs[cb];
#pragma unroll
        for (int s = 0; s < 2; ++s) {
            bf16x8 a[2], b2[4];
#pragma unroll
            for (int i = 0; i < 2; ++i) {
                int row = wm + i * 16 + r16;
                int au = (s * 4 + quad) ^ (row & 7);
                a[i] = *(const bf16x8*)(Ab + row * 64 + au * 8);
            }
#pragma unroll
            for (int j = 0; j < 4; ++j) {
                int row = wn + j * 16 + r16;
                int bu = (s * 4 + quad) ^ (row & 7);
                b2[j] = *(const bf16x8*)(Bb + row * 64 + bu * 8);
            }
#pragma unroll
            for (int i = 0; i < 2; ++i)
#pragma unroll
                for (int j = 0; j < 4; ++j)
                    acc[i][j] = __builtin_amdgcn_mfma_f32_16x16x32_bf16(a[i], b2[j], acc[i][j], 0, 0, 0);
        }
    }
    ushort* O = (m < 2) ? Yn : Ys;
    int cb0 = (m < 2) ? n0 : (n0 - 256);       // col base within target buffer
#pragma unroll
    for (int i = 0; i < 2; ++i)
#pragma unroll
        for (int j = 0; j < 4; ++j) {
            int col = cb0 + wn + j * 16 + r16;
#pragma unroll
            for (int rg = 0; rg < 4; ++rg) {
                int row = m0 + wm + i * 16 + quad * 4 + rg;
                O[(size_t)row * HID + col] = f2bf(acc[i][j][rg]);
            }
        }
}

// ---------------- fused gather + combine: one 64-lane wave per node, half-wave rows.
__device__ __forceinline__ void acc8(float* A, ushort8v y) {
#pragma unroll
    for (int i = 0; i < 8; ++i) A[i] += bf2f((ushort)y[i]);
}

__global__ __launch_bounds__(256) void gather_kernel(const ushort* __restrict__ Yn,
                                                     const ushort* __restrict__ Ys,
                                                     const int* __restrict__ off,
                                                     const int* __restrict__ eidx,
                                                     const float* __restrict__ bias,
                                                     ushort* __restrict__ h, int n_nodes) {
    int tid = threadIdx.x;
    int v = blockIdx.x * 4 + (tid >> 6);
    if (v >= n_nodes) return;
    int lane = tid & 63;
    int half = lane >> 5, sub = lane & 31;
    int c8 = sub << 3;                         // 8 cols per lane
    int e0 = off[v], e1 = off[v + 1];
    float accA[8] = {0.f, 0.f, 0.f, 0.f, 0.f, 0.f, 0.f, 0.f};
    float accB[8] = {0.f, 0.f, 0.f, 0.f, 0.f, 0.f, 0.f, 0.f};
    for (int base = e0; base < e1; base += 64) {
        int ecnt = min(64, e1 - base);
        int ev = (lane < ecnt) ? eidx[base + lane] : 0;   // coalesced index prefetch
        int j = 0;
        for (; j + 16 <= ecnt; j += 16) {
            int s0 = __shfl(ev, j + 0 + half, 64);
            int s1 = __shfl(ev, j + 2 + half, 64);
            int s2 = __shfl(ev, j + 4 + half, 64);
            int s3 = __shfl(ev, j + 6 + half, 64);
            int s4 = __shfl(ev, j + 8 + half, 64);
            int s5 = __shfl(ev, j + 10 + half, 64);
            int s6 = __shfl(ev, j + 12 + half, 64);
            int s7 = __shfl(ev, j + 14 + half, 64);
            ushort8v y0 = *(const ushort8v*)(Yn + (size_t)s0 * HID + c8);
            ushort8v y1 = *(const ushort8v*)(Yn + (size_t)s1 * HID + c8);
            ushort8v y2 = *(const ushort8v*)(Yn + (size_t)s2 * HID + c8);
            ushort8v y3 = *(const ushort8v*)(Yn + (size_t)s3 * HID + c8);
            ushort8v y4 = *(const ushort8v*)(Yn + (size_t)s4 * HID + c8);
            ushort8v y5 = *(const ushort8v*)(Yn + (size_t)s5 * HID + c8);
            ushort8v y6 = *(const ushort8v*)(Yn + (size_t)s6 * HID + c8);
            ushort8v y7 = *(const ushort8v*)(Yn + (size_t)s7 * HID + c8);
            acc8(accA, y0); acc8(accB, y1); acc8(accA, y2); acc8(accB, y3);
            acc8(accA, y4); acc8(accB, y5); acc8(accA, y6); acc8(accB, y7);
        }
        for (; j < ecnt; j += 2) {             // tail: one row per half
            int idx = j + half;
            if (idx < ecnt) {
                int s = __shfl(ev, idx, 64);
                ushort8v y = *(const ushort8v*)(Yn + (size_t)s * HID + c8);
                acc8(accA, y);
            }
        }
    }
#pragma unroll
    for (int i = 0; i < 8; ++i) {
        accA[i] += accB[i];
        accA[i] += __shfl_xor(accA[i], 32, 64);
    }
    if (half == 0) {
        ushort8v sv = *(const ushort8v*)(Ys + (size_t)v * HID + c8);
        float bb[8];
        *(float4*)(bb)     = *(const float4*)(bias + c8);
        *(float4*)(bb + 4) = *(const float4*)(bias + c8 + 4);
        float invd = 1.0f / fmaxf((float)(e1 - e0), 1.0f);
        ushort8v r;
#pragma unroll
        for (int i = 0; i < 8; ++i)
            r[i] = f2bf(fmaxf(accA[i] * invd + bf2f((ushort)sv[i]) + bb[i], 0.f));
        *(ushort8v*)(h + (size_t)v * HID + c8) = r;
    }
}

// ---------------- segmented mean-pool (batch sorted), bf16 in, fp32 accumulate
__global__ void pool_kernel(const ushort* __restrict__ h, const int* __restrict__ batch,
                            float* __restrict__ pooled, float* __restrict__ cnt, int n_nodes) {
    int f = threadIdx.x;                     // 256 features
    int v0 = blockIdx.x * 64;
    int vend = min(v0 + 64, n_nodes);
    if (v0 >= n_nodes) return;
    int cur = batch[v0];
    float acc = 0.f, ac = 0.f;
    for (int v = v0; v < vend; ++v) {
        int g = batch[v];
        if (g != cur) {
            atomicAdd(&pooled[cur * HID + f], acc);
            if (f == 0) atomicAdd(&cnt[cur], ac);
            acc = 0.f; ac = 0.f; cur = g;
        }
        acc += bf2f(h[(size_t)v * HID + f]);
        ac += 1.0f;
    }
    atomicAdd(&pooled[cur * HID + f], acc);
    if (f == 0) atomicAdd(&cnt[cur], ac);
}

// ---------------- MLP head: out[g] = relu(pooled_mean @ fc1w + fc1b) @ fc2w + fc2b
__global__ void head_kernel(const float* __restrict__ pooled, const float* __restrict__ cnt,
                            const float* __restrict__ fc1w, const float* __restrict__ fc1b,
                            const float* __restrict__ fc2w, const float* __restrict__ fc2b,
                            float* __restrict__ out) {
    int g = blockIdx.x, j = threadIdx.x;     // 128 threads
    __shared__ float p[256];
    __shared__ float hid[128];
    float inv = 1.0f / fmaxf(cnt[g], 1.0f);
    p[j] = pooled[g * HID + j] * inv;
    p[j + 128] = pooled[g * HID + 128 + j] * inv;
    __syncthreads();
    float a = fc1b[j];
    for (int f = 0; f < 256; ++f) a += p[f] * fc1w[f * 128 + j];
    hid[j] = fmaxf(a, 0.f);
    __syncthreads();
    if (j < 2) {
        float o = fc2b[j];
        for (int t = 0; t < 128; ++t) o += hid[t] * fc2w[t * 2 + j];
        out[g * 2 + j] = o;
    }
}

extern "C" void kernel_launch(void* const* d_in, const int* in_sizes, int n_in,
                              void* d_out, int out_size, void* d_ws, size_t ws_size,
                              hipStream_t stream) {
    const float* x    = (const float*)d_in[0];
    const int*   ei   = (const int*)d_in[1];
    const int*   batch= (const int*)d_in[2];
    const float* W1n  = (const float*)d_in[3];
    const float* W1s  = (const float*)d_in[4];
    const float* b1   = (const float*)d_in[5];
    const float* W2n  = (const float*)d_in[6];
    const float* W2s  = (const float*)d_in[7];
    const float* b2   = (const float*)d_in[8];
    const float* fc1w = (const float*)d_in[9];
    const float* fc1b = (const float*)d_in[10];
    const float* fc2w = (const float*)d_in[11];
    const float* fc2b = (const float*)d_in[12];
    float* out = (float*)d_out;

    const int n_nodes = in_sizes[2];
    const int n_edges = in_sizes[1] / 2;
    const int in_dim  = in_sizes[0] / n_nodes;   // 512
    const int Mpad    = (n_nodes + 63) & ~63;    // 20032
    const int nb      = (n_nodes + 255) / 256;   // scan chunks (79)
    const int nG      = Mpad / 64;               // A-stripes (313)
    const int* src = ei;
    const int* dst = ei + n_edges;

    // workspace layout, 256B-aligned. degi+pooled adjacent -> one memset. (no xb!)
    char* wsb = (char*)d_ws;
    size_t cur = 0;
    auto alloc = [&](size_t nbytes) { size_t o = cur; cur = (cur + nbytes + 255) & ~(size_t)255; return o; };
    size_t o_degi = alloc((size_t)n_nodes * 4);
    size_t o_pool = alloc((size_t)16 * HID * 4 + 16 * 4);
    size_t zero_end = cur;                       // memset span [o_degi, zero_end)
    size_t o_off  = alloc((size_t)(n_nodes + 1) * 4);
    size_t o_cur  = alloc((size_t)n_nodes * 4);
    size_t o_part = alloc((size_t)nb * 4);
    size_t o_eidx = alloc((size_t)n_edges * 4);
    size_t o_w1   = alloc((size_t)NCOL * in_dim * 2);
    size_t o_w2   = alloc((size_t)NCOL * HID * 2);
    size_t o_hb   = alloc((size_t)Mpad * HID * 2);
    size_t o_yn   = alloc((size_t)Mpad * HID * 2);
    size_t o_ys   = alloc((size_t)Mpad * HID * 2);
    (void)ws_size;

    int*    degi    = (int*)(wsb + o_degi);
    float*  pooled  = (float*)(wsb + o_pool);
    float*  cnt     = pooled + 16 * HID;
    int*    off     = (int*)(wsb + o_off);
    int*    cursor  = (int*)(wsb + o_cur);
    int*    partials= (int*)(wsb + o_part);
    int*    eidx    = (int*)(wsb + o_eidx);
    ushort* w1t     = (ushort*)(wsb + o_w1);
    ushort* w2t     = (ushort*)(wsb + o_w2);
    ushort* hb      = (ushort*)(wsb + o_hb);
    ushort* Yn      = (ushort*)(wsb + o_yn);
    ushort* Ys      = (ushort*)(wsb + o_ys);

    hipMemsetAsync(wsb + o_degi, 0, zero_end - o_degi, stream);

    // ---- prep (lite): packT W1 | packT W2 | degree histogram
    int nb_w1  = (NCOL * in_dim + 255) / 256;
    int nb_w2  = (NCOL * HID + 255) / 256;
    int nb_deg = (n_edges + 255) / 256;
    prep_kernel<<<nb_w1 + nb_w2 + nb_deg, 256, 0, stream>>>(
        W1n, W1s, w1t, in_dim, W2n, W2s, w2t, HID, dst, degi, n_edges, nb_w1, nb_w2);

    // ---- CSR prefix: chunk sums -> fused prefix+rescan
    psum_kernel<<<nb, 256, 0, stream>>>(degi, partials, n_nodes);
    scan2_kernel<<<nb, 256, 0, stream>>>(degi, partials, off, cursor, n_nodes, nb);

    int gemm_blocks = 8 * 4 * ((nG + 7) / 8);    // 1280
    int fill_blocks = (n_edges + 255) / 256;     // 625
    int gather_blocks = (n_nodes + 3) / 4;

    // ---- layer 1: gemm (A = x in f32, staged+converted) fused with CSR fill
    gemm_kernel<1, 1><<<gemm_blocks + fill_blocks, 256, 0, stream>>>(
        x, w1t, Yn, Ys, in_dim, nG, n_nodes, gemm_blocks,
        src, dst, cursor, eidx, n_edges);
    gather_kernel<<<gather_blocks, 256, 0, stream>>>(Yn, Ys, off, eidx, b1, hb, n_nodes);

    // ---- layer 2: gemm (A = hb bf16, global_load_lds path)
    gemm_kernel<0, 0><<<gemm_blocks, 256, 0, stream>>>(
        hb, w2t, Yn, Ys, HID, nG, 0, gemm_blocks,
        nullptr, nullptr, nullptr, nullptr, 0);
    gather_kernel<<<gather_blocks, 256, 0, stream>>>(Yn, Ys, off, eidx, b2, hb, n_nodes);

    // ---- pool + head
    pool_kernel<<<(n_nodes + 63) / 64, 256, 0, stream>>>(hb, batch, pooled, cnt, n_nodes);
    head_kernel<<<16, 128, 0, stream>>>(pooled, cnt, fc1w, fc1b, fc2w, fc2b, out);
}